// Round 8
// baseline (230.550 us; speedup 1.0000x reference)
//
#include <hip/hip_runtime.h>
#include <cstdint>

#define NB   64
#define ND   256
#define NHW  1024
#define NTOK 65536
#define NDC  128
#define NK   1024

#define OFF_LOSS 16777216
#define OFF_Q    16777217
#define OFF_PERP 16842753

#define GAPTHR 1e-3f
#define NEGINF (-3.402823466e38f)

typedef short short8 __attribute__((ext_vector_type(8)));
typedef float f32x4 __attribute__((ext_vector_type(4)));

__device__ __forceinline__ unsigned short f2bf(float f) {
  unsigned u = __float_as_uint(f);
  u += 0x7FFFu + ((u >> 16) & 1u);
  return (unsigned short)(u >> 16);
}
__device__ __forceinline__ float bf2f(unsigned short h) {
  return __uint_as_float(((unsigned)h) << 16);
}

__device__ __forceinline__ void gll16(const void* g, void* l) {
  __builtin_amdgcn_global_load_lds(
      (const __attribute__((address_space(1))) unsigned int*)g,
      (__attribute__((address_space(3))) unsigned int*)l, 16, 0, 0);
}

// ---------- init: bf16 splits (codebook for dist, preW/postW planes), norms, zeros ----------
__global__ __launch_bounds__(256) void k_init(
    const float* __restrict__ lut, const float* __restrict__ preW,
    const float* __restrict__ postW,
    unsigned short* __restrict__ ch,
    unsigned short* __restrict__ pwh, unsigned short* __restrict__ pwl,
    unsigned short* __restrict__ qwh, unsigned short* __restrict__ qwl,
    float* __restrict__ nhn, double* __restrict__ cn2d,
    int* __restrict__ counts, double* __restrict__ lossAcc, int* __restrict__ ctr) {
  int tid = blockIdx.x * 256 + threadIdx.x;
  int stride = gridDim.x * 256;
  for (int i = tid; i < NK * NDC; i += stride) {   // lut -> split bf16 ch[code][256] (dist)
    int code = i >> 7, c = i & 127;
    float f = lut[i];
    unsigned short h1 = f2bf(f);
    float r = f - bf2f(h1);
    ch[code * 256 + c] = h1;
    ch[code * 256 + 128 + c] = f2bf(r);
  }
  for (int i = tid; i < NDC * ND; i += stride) {   // preW [DC][D] -> trunc-split planes
    float f = preW[i];
    unsigned u = __float_as_uint(f);
    float lf = f - __uint_as_float(u & 0xffff0000u);
    pwh[i] = (unsigned short)(u >> 16);
    pwl[i] = (unsigned short)(__float_as_uint(lf) >> 16);
  }
  for (int i = tid; i < ND * NDC; i += stride) {   // postW [D][DC] -> trunc-split planes
    float f = postW[i];
    unsigned u = __float_as_uint(f);
    float lf = f - __uint_as_float(u & 0xffff0000u);
    qwh[i] = (unsigned short)(u >> 16);
    qwl[i] = (unsigned short)(__float_as_uint(lf) >> 16);
  }
  if (tid < NK) {
    float s = 0.f;
    double sd = 0.0;
    for (int c = 0; c < NDC; c++) {
      float v = lut[tid * NDC + c];
      s = fmaf(v, v, s);
      sd = fma((double)v, (double)v, sd);
    }
    nhn[tid] = -0.5f * s;
    cn2d[tid] = sd;
    counts[tid] = 0;
  }
  if (tid == 0) { *lossAcc = 0.0; *ctr = 0; }
}

// ---------- pre-conv via bf16-split MFMA: x tile staged to LDS via global_load_lds ----------
__global__ __launch_bounds__(256, 2) void k_preconv(
    const float* __restrict__ x, const unsigned short* __restrict__ pwh,
    const unsigned short* __restrict__ pwl, const float* __restrict__ pre_b,
    float* __restrict__ zf) {
  __shared__ __align__(16) float xt[256 * 64];   // 64 KB: [ch][token], odd-(k&8) rows XOR 64B
  int bx = blockIdx.x;                           // 1024 blocks: 64 tokens each
  int b = bx >> 4, p0 = (bx & 15) * 64;
  int tid = threadIdx.x;
  int lane = tid & 63, w = tid >> 6;
  int g = lane >> 4, l15 = lane & 15;
  const char* xbb = (const char*)(x + (size_t)b * (ND * NHW) + p0);

  // stage all 256 rows (64 floats each) — 16 gll16 per thread, swizzled global source
  #pragma unroll
  for (int r = 0; r < 16; ++r) {
    int o = r * 4096 + tid * 16;
    int row = o >> 8;
    int col = (o & 255) ^ ((row & 8) ? 64 : 0);
    gll16(xbb + (size_t)row * (NHW * 4) + col, ((char*)xt) + o);
  }
  asm volatile("s_waitcnt vmcnt(0)" ::: "memory");
  __syncthreads();

  f32x4 acc[8];
  #pragma unroll
  for (int rt = 0; rt < 8; ++rt) acc[rt] = (f32x4){0.f, 0.f, 0.f, 0.f};

  int p4 = (w * 16 + l15) * 4;
  #pragma unroll
  for (int c = 0; c < 8; ++c) {
    int k0 = c * 32;
    short8 bh, bl;
    #pragma unroll
    for (int j = 0; j < 8; ++j) {
      int k = k0 + g * 8 + j;
      float f = *(const float*)((const char*)xt + k * 256 + (p4 ^ ((k & 8) ? 64 : 0)));
      unsigned u = __float_as_uint(f);
      float lf = f - __uint_as_float(u & 0xffff0000u);
      bh[j] = (short)(u >> 16);
      bl[j] = (short)(__float_as_uint(lf) >> 16);
    }
    #pragma unroll
    for (int rt = 0; rt < 8; ++rt) {
      short8 ah = *reinterpret_cast<const short8*>(&pwh[(rt * 16 + l15) * ND + k0 + g * 8]);
      short8 al = *reinterpret_cast<const short8*>(&pwl[(rt * 16 + l15) * ND + k0 + g * 8]);
      acc[rt] = __builtin_amdgcn_mfma_f32_16x16x32_bf16(ah, bh, acc[rt], 0, 0, 0);
      acc[rt] = __builtin_amdgcn_mfma_f32_16x16x32_bf16(ah, bl, acc[rt], 0, 0, 0);
      acc[rt] = __builtin_amdgcn_mfma_f32_16x16x32_bf16(al, bh, acc[rt], 0, 0, 0);
    }
  }
  int n = bx * 64 + w * 16 + l15;
  #pragma unroll
  for (int rt = 0; rt < 8; ++rt) {
    float4 bb = *reinterpret_cast<const float4*>(&pre_b[rt * 16 + g * 4]);
    float4 v;
    v.x = acc[rt][0] + bb.x;
    v.y = acc[rt][1] + bb.y;
    v.z = acc[rt][2] + bb.z;
    v.w = acc[rt][3] + bb.w;
    *reinterpret_cast<float4*>(&zf[(size_t)n * NDC + rt * 16 + g * 4]) = v;
  }
}

// ---------- distance via bf16-split MFMA + fused loss: argmax_k (z.c - 0.5|c|^2) ----------
__global__ __launch_bounds__(256, 2) void k_dist(
    const float* __restrict__ zf, const unsigned short* __restrict__ ch,
    const float* __restrict__ nhn,
    int* __restrict__ q, int* __restrict__ list, int* __restrict__ ctr,
    double* __restrict__ lossAcc) {
  __shared__ __align__(16) short chbuf[2][16384];   // 2 x 32 KB code chunk (swizzled image)
  __shared__ float HnLds[NK];                       // 4 KB (negated half-norms)
  __shared__ float zn2Lds[4][2][16];                // |z|^2 per token
  __shared__ float red[256];
  int tid = threadIdx.x;
  int lane = tid & 63, w = tid >> 6;
  int g = lane >> 4;
  int n0 = blockIdx.x * 128;

  for (int i = tid; i < NK; i += 256) HnLds[i] = nhn[i];

  // A fragments: 32 tokens per wave, bf16-split in registers (z1 in [0..3], z2 in [4..7])
  short8 az[2][8];
  {
    int arow = lane & 15;
    #pragma unroll
    for (int rt = 0; rt < 2; ++rt) {
      const float* zr = zf + (size_t)(n0 + w * 32 + rt * 16 + arow) * NDC;
      float sq = 0.f;
      #pragma unroll
      for (int f = 0; f < 4; ++f) {
        const float* p = zr + f * 32 + g * 8;
        float4 v0 = *reinterpret_cast<const float4*>(p);
        float4 v1 = *reinterpret_cast<const float4*>(p + 4);
        float vv[8] = {v0.x, v0.y, v0.z, v0.w, v1.x, v1.y, v1.z, v1.w};
        short8 hi, lo;
        #pragma unroll
        for (int j = 0; j < 8; ++j) {
          sq = fmaf(vv[j], vv[j], sq);
          unsigned short h1 = f2bf(vv[j]);
          float r = vv[j] - bf2f(h1);
          hi[j] = (short)h1;
          lo[j] = (short)f2bf(r);
        }
        az[rt][f] = hi;
        az[rt][4 + f] = lo;
      }
      sq += __shfl_xor(sq, 16, 64);
      sq += __shfl_xor(sq, 32, 64);
      if (g == 0) zn2Lds[w][rt][arow] = sq;   // full |z|^2 of token n0+w*32+rt*16+arow
    }
  }

  float best[2][4], sec[2][4];
  int bidx[2][4];
  #pragma unroll
  for (int rt = 0; rt < 2; ++rt)
    #pragma unroll
    for (int r = 0; r < 4; ++r) { best[rt][r] = NEGINF; sec[rt][r] = NEGINF; bidx[rt][r] = 0; }

  const char* chg = (const char*)ch;
  // stage chunk 0
  {
    const char* gb = chg + 0;
    #pragma unroll
    for (int rr = 0; rr < 8; ++rr) {
      int o = rr * 4096 + tid * 16;
      int so = o ^ (((o >> 9) & 7) << 4);
      gll16(gb + so, ((char*)&chbuf[0][0]) + o);
    }
  }
  asm volatile("s_waitcnt vmcnt(0)" ::: "memory");
  __syncthreads();

  int cur = 0;
  for (int chunk = 0; chunk < 16; ++chunk) {
    if (chunk < 15) {                         // prefetch next chunk into other buffer
      const char* gb = chg + (chunk + 1) * 32768;
      #pragma unroll
      for (int rr = 0; rr < 8; ++rr) {
        int o = rr * 4096 + tid * 16;
        int so = o ^ (((o >> 9) & 7) << 4);
        gll16(gb + so, ((char*)&chbuf[cur ^ 1][0]) + o);
      }
    }
    const char* cb = (const char*)&chbuf[cur][0];
    for (int ct = 0; ct < 4; ++ct) {
      int codeg = chunk * 64 + ct * 16 + (lane & 15);
      float nh = HnLds[codeg];
      short8 bc[8];
      #pragma unroll
      for (int f = 0; f < 8; ++f) {
        int byte = ((lane & 15) + ct * 16) * 512 + f * 64 + g * 16;
        byte ^= ((lane & 7) << 4);
        bc[f] = *reinterpret_cast<const short8*>(cb + byte);
      }
      f32x4 acc0 = {nh, nh, nh, nh};
      f32x4 acc1 = {nh, nh, nh, nh};
      #pragma unroll
      for (int j = 0; j < 4; ++j) {
        acc0 = __builtin_amdgcn_mfma_f32_16x16x32_bf16(az[0][j], bc[j], acc0, 0, 0, 0);
        acc1 = __builtin_amdgcn_mfma_f32_16x16x32_bf16(az[1][j], bc[j], acc1, 0, 0, 0);
        acc0 = __builtin_amdgcn_mfma_f32_16x16x32_bf16(az[0][j], bc[4 + j], acc0, 0, 0, 0);
        acc1 = __builtin_amdgcn_mfma_f32_16x16x32_bf16(az[1][j], bc[4 + j], acc1, 0, 0, 0);
        acc0 = __builtin_amdgcn_mfma_f32_16x16x32_bf16(az[0][4 + j], bc[j], acc0, 0, 0, 0);
        acc1 = __builtin_amdgcn_mfma_f32_16x16x32_bf16(az[1][4 + j], bc[j], acc1, 0, 0, 0);
      }
      #pragma unroll
      for (int r = 0; r < 4; ++r) {
        float s0 = acc0[r];
        bool t0 = s0 > best[0][r];
        bidx[0][r] = t0 ? codeg : bidx[0][r];
        sec[0][r] = fmaxf(sec[0][r], fminf(s0, best[0][r]));
        best[0][r] = fmaxf(s0, best[0][r]);
        float s1 = acc1[r];
        bool t1 = s1 > best[1][r];
        bidx[1][r] = t1 ? codeg : bidx[1][r];
        sec[1][r] = fmaxf(sec[1][r], fminf(s1, best[1][r]));
        best[1][r] = fmaxf(s1, best[1][r]);
      }
    }
    asm volatile("s_waitcnt vmcnt(0)" ::: "memory");
    __syncthreads();
    cur ^= 1;
  }

  // cross-lane merge over the 16 code-columns (lanes sharing g), write q/list, loss partials
  float lsum = 0.f;
  #pragma unroll
  for (int rt = 0; rt < 2; ++rt) {
    #pragma unroll
    for (int r = 0; r < 4; ++r) {
      float b = best[rt][r];
      float s2 = sec[rt][r];
      int bi_ = bidx[rt][r];
      #pragma unroll
      for (int m = 1; m < 16; m <<= 1) {
        float ob = __shfl_xor(b, m, 64);
        float os = __shfl_xor(s2, m, 64);
        int oi = __shfl_xor(bi_, m, 64);
        float ns = fmaxf(fmaxf(s2, os), fminf(b, ob));
        bool take = (ob > b) || (ob == b && oi < bi_);
        b = take ? ob : b;
        bi_ = take ? oi : bi_;
        s2 = ns;
      }
      if ((lane & 15) == 0) {
        int token = n0 + w * 32 + rt * 16 + g * 4 + r;
        q[token] = bi_;
        if (b - s2 < GAPTHR) {
          int pos = atomicAdd(ctr, 1);
          list[pos] = token;
        }
        lsum += zn2Lds[w][rt][g * 4 + r] - 2.0f * b;  // |z - c|^2 = |z|^2 - 2 s*
      }
    }
  }
  red[tid] = lsum;
  __syncthreads();
  for (int s = 128; s > 0; s >>= 1) {
    if (tid < s) red[tid] += red[tid + s];
    __syncthreads();
  }
  if (tid == 0) atomicAdd(lossAcc, (double)red[0]);
}

// ---------- rescore v3: 4 tokens/block-iter, fully thread-parallel f64 ----------
__global__ __launch_bounds__(256) void k_rescore(
    const float* __restrict__ x, const float* __restrict__ preW,
    const float* __restrict__ pre_b, const float* __restrict__ lut,
    const double* __restrict__ cn2d,
    const int* __restrict__ list, const int* __restrict__ ctr, int* __restrict__ q) {
  __shared__ float xs[4][256];
  __shared__ double zs[4][128];
  __shared__ double rd[4][256];
  __shared__ int    rc[4][256];
  int nf = *ctr;
  int tid = threadIdx.x;
  int w = tid >> 6, lane = tid & 63;
  for (int g0 = blockIdx.x * 4; g0 < nf; g0 += gridDim.x * 4) {
    int nt = nf - g0; if (nt > 4) nt = 4;
    // phase 0: stage the 4 x-columns (d = tid)
    #pragma unroll
    for (int t = 0; t < 4; ++t) {
      int token = list[g0 + (t < nt ? t : 0)];
      int b = token >> 10, p = token & 1023;
      xs[t][tid] = x[(size_t)(b * ND + tid) * NHW + p];
    }
    __syncthreads();
    // phase 1: z in f64 — 512 (token,dc) tasks over 256 threads x 2 reps
    #pragma unroll
    for (int rep = 0; rep < 2; ++rep) {
      int idx = rep * 256 + tid;
      int t = idx >> 7, dc = idx & 127;
      double acc = (double)pre_b[dc];
      const float* wr = preW + (size_t)dc * ND;
      #pragma unroll 4
      for (int d = 0; d < ND; d += 4) {
        float4 wv = *reinterpret_cast<const float4*>(wr + d);
        acc = fma((double)wv.x, (double)xs[t][d + 0], acc);
        acc = fma((double)wv.y, (double)xs[t][d + 1], acc);
        acc = fma((double)wv.z, (double)xs[t][d + 2], acc);
        acc = fma((double)wv.w, (double)xs[t][d + 3], acc);
      }
      zs[t][dc] = acc;
    }
    __syncthreads();
    // phase 2: each thread scans 4 codes (ascending) for all 4 tokens
    double bd[4]; int bc_[4];
    #pragma unroll
    for (int t = 0; t < 4; ++t) { bd[t] = 1e300; bc_[t] = 0x7fffffff; }
    for (int cc = 0; cc < 4; ++cc) {
      int c = cc * 256 + tid;
      const float* cr = lut + (size_t)c * NDC;
      double a0 = 0.0, a1 = 0.0, a2 = 0.0, a3 = 0.0;
      #pragma unroll 4
      for (int k = 0; k < NDC; ++k) {
        double lc = (double)cr[k];
        a0 = fma(zs[0][k], lc, a0);
        a1 = fma(zs[1][k], lc, a1);
        a2 = fma(zs[2][k], lc, a2);
        a3 = fma(zs[3][k], lc, a3);
      }
      double cn = cn2d[c];
      double d0 = cn - 2.0 * a0; if (d0 < bd[0]) { bd[0] = d0; bc_[0] = c; }
      double d1 = cn - 2.0 * a1; if (d1 < bd[1]) { bd[1] = d1; bc_[1] = c; }
      double d2 = cn - 2.0 * a2; if (d2 < bd[2]) { bd[2] = d2; bc_[2] = c; }
      double d3 = cn - 2.0 * a3; if (d3 < bd[3]) { bd[3] = d3; bc_[3] = c; }
    }
    #pragma unroll
    for (int t = 0; t < 4; ++t) { rd[t][tid] = bd[t]; rc[t][tid] = bc_[t]; }
    __syncthreads();
    // phase 3: wave w reduces token w (tree, lowest-index tie-break)
    {
      double b_ = rd[w][lane]; int c_ = rc[w][lane];
      #pragma unroll
      for (int s = 64; s < 256; s += 64) {
        double ob = rd[w][lane + s]; int oc = rc[w][lane + s];
        if (ob < b_ || (ob == b_ && oc < c_)) { b_ = ob; c_ = oc; }
      }
      #pragma unroll
      for (int m = 1; m < 64; m <<= 1) {
        double ob = __shfl_xor(b_, m, 64);
        int oc = __shfl_xor(c_, m, 64);
        if (ob < b_ || (ob == b_ && oc < c_)) { b_ = ob; c_ = oc; }
      }
      if (lane == 0 && w < nt) q[list[g0 + w]] = c_;
    }
    __syncthreads();
  }
}

// ---------- post-conv via bf16-split MFMA: lut gathers hoisted, float4 stores ----------
__global__ __launch_bounds__(256, 3) void k_post(
    const float* __restrict__ lut,
    const int* __restrict__ q, const unsigned short* __restrict__ qwh,
    const unsigned short* __restrict__ qwl, const float* __restrict__ post_b,
    float* __restrict__ out,
    int* __restrict__ counts, float* __restrict__ outq) {
  int bx = blockIdx.x;                       // 1024 blocks: (512 token sets) x (2 o-halves)
  int n0 = (bx >> 1) * 128;
  int oh = (bx & 1) * 128;
  int b = n0 >> 10, p0 = n0 & 1023;
  int tid = threadIdx.x;
  int lane = tid & 63, w = tid >> 6;
  int g = lane >> 4, l15 = lane & 15;

  int qv[2];
  #pragma unroll
  for (int ct = 0; ct < 2; ++ct) qv[ct] = q[n0 + w * 32 + ct * 16 + l15];

  // hoist ALL lut gathers (the long dependent chain) before any compute
  float4 ga[2][4][2];
  #pragma unroll
  for (int ct = 0; ct < 2; ++ct) {
    const float* xr0 = lut + (size_t)qv[ct] * NDC + g * 8;
    #pragma unroll
    for (int ks = 0; ks < 4; ++ks) {
      ga[ct][ks][0] = *reinterpret_cast<const float4*>(xr0 + ks * 32);
      ga[ct][ks][1] = *reinterpret_cast<const float4*>(xr0 + ks * 32 + 4);
    }
  }

  // histogram + q_map: each block handles its own 64-token half
  if (tid < 64) {
    int n = n0 + ((bx & 1) << 6) + tid;
    int c = q[n];
    atomicAdd(&counts[c], 1);
    outq[n] = (float)c;
  }

  // convert all gathers to bf16-split A fragments
  short8 ah[2][4], al[2][4];
  #pragma unroll
  for (int ct = 0; ct < 2; ++ct)
    #pragma unroll
    for (int ks = 0; ks < 4; ++ks) {
      float vv[8] = {ga[ct][ks][0].x, ga[ct][ks][0].y, ga[ct][ks][0].z, ga[ct][ks][0].w,
                     ga[ct][ks][1].x, ga[ct][ks][1].y, ga[ct][ks][1].z, ga[ct][ks][1].w};
      #pragma unroll
      for (int j = 0; j < 8; ++j) {
        unsigned u = __float_as_uint(vv[j]);
        float lf = vv[j] - __uint_as_float(u & 0xffff0000u);
        ah[ct][ks][j] = (short)(u >> 16);
        al[ct][ks][j] = (short)(__float_as_uint(lf) >> 16);
      }
    }

  f32x4 acc[8][2];
  #pragma unroll
  for (int nt = 0; nt < 8; ++nt)
    #pragma unroll
    for (int ct = 0; ct < 2; ++ct) acc[nt][ct] = (f32x4){0.f, 0.f, 0.f, 0.f};

  #pragma unroll
  for (int ks = 0; ks < 4; ++ks) {
    int k0 = ks * 32;
    #pragma unroll
    for (int nt = 0; nt < 8; ++nt) {
      short8 bh = *reinterpret_cast<const short8*>(&qwh[(size_t)(oh + nt * 16 + l15) * NDC + k0 + g * 8]);
      short8 bl = *reinterpret_cast<const short8*>(&qwl[(size_t)(oh + nt * 16 + l15) * NDC + k0 + g * 8]);
      #pragma unroll
      for (int ct = 0; ct < 2; ++ct) {
        acc[nt][ct] = __builtin_amdgcn_mfma_f32_16x16x32_bf16(ah[ct][ks], bh, acc[nt][ct], 0, 0, 0);
        acc[nt][ct] = __builtin_amdgcn_mfma_f32_16x16x32_bf16(al[ct][ks], bh, acc[nt][ct], 0, 0, 0);
        acc[nt][ct] = __builtin_amdgcn_mfma_f32_16x16x32_bf16(ah[ct][ks], bl, acc[nt][ct], 0, 0, 0);
      }
    }
  }
  // store: acc[nt][ct] holds 4 consecutive tokens (p) at fixed o -> float4 stores
  #pragma unroll
  for (int nt = 0; nt < 8; ++nt) {
    int o = oh + nt * 16 + l15;
    float bias = post_b[o];
    float* orow = out + (size_t)(b * ND + o) * NHW;
    #pragma unroll
    for (int ct = 0; ct < 2; ++ct) {
      int p = p0 + w * 32 + ct * 16 + g * 4;
      float4 v;
      v.x = acc[nt][ct][0] + bias;
      v.y = acc[nt][ct][1] + bias;
      v.z = acc[nt][ct][2] + bias;
      v.w = acc[nt][ct][3] + bias;
      *reinterpret_cast<float4*>(orow + p) = v;
    }
  }
}

// ---------- finalize ----------
__global__ __launch_bounds__(256) void k_fin(
    const double* __restrict__ lossAcc, const int* __restrict__ counts,
    float* __restrict__ out_loss, float* __restrict__ out_perp) {
  __shared__ float red[256];
  int tid = threadIdx.x;
  float h = 0.f;
  for (int i = tid; i < NK; i += 256) {
    float e = (float)counts[i] * (1.0f / (float)NTOK);
    h += e * logf(e + 1e-10f);
  }
  red[tid] = h;
  __syncthreads();
  for (int s = 128; s > 0; s >>= 1) {
    if (tid < s) red[tid] += red[tid + s];
    __syncthreads();
  }
  if (tid == 0) {
    *out_perp = expf(-red[0]);
    *out_loss = (float)(*lossAcc / ((double)NTOK * (double)NDC));
  }
}

extern "C" void kernel_launch(void* const* d_in, const int* in_sizes, int n_in,
                              void* d_out, int out_size, void* d_ws, size_t ws_size,
                              hipStream_t stream) {
  const float* x     = (const float*)d_in[0];
  const float* preW  = (const float*)d_in[1];
  const float* preb  = (const float*)d_in[2];
  const float* postW = (const float*)d_in[3];
  const float* postb = (const float*)d_in[4];
  const float* lut   = (const float*)d_in[5];
  float* out = (float*)d_out;

  char* ws = (char*)d_ws;
  float*          zf      = (float*)(ws);                      // 33,554,432 B
  unsigned short* ch      = (unsigned short*)(ws + 33554432);  //   524,288 B
  unsigned short* pwh     = (unsigned short*)(ws + 34078720);  //    65,536 B
  unsigned short* pwl     = (unsigned short*)(ws + 34144256);  //    65,536 B
  unsigned short* qwh     = (unsigned short*)(ws + 34209792);  //    65,536 B
  unsigned short* qwl     = (unsigned short*)(ws + 34275328);  //    65,536 B
  float*          nhn     = (float*)(ws + 34340864);           //     4,096 B
  int*            q       = (int*)  (ws + 34344960);           //   262,144 B
  int*            list    = (int*)  (ws + 34607104);           //   262,144 B
  int*            counts  = (int*)  (ws + 34869248);           //     4,096 B
  double*         lossAcc = (double*)(ws + 34873344);          //         8 B
  int*            ctr     = (int*)  (ws + 34873352);           //         4 B
  double*         cn2d    = (double*)(ws + 34873360);          //     8,192 B

  float* out_loss = out + OFF_LOSS;
  float* out_q    = out + OFF_Q;
  float* out_perp = out + OFF_PERP;

  hipLaunchKernelGGL(k_init, dim3(512), dim3(256), 0, stream,
                     lut, preW, postW, ch, pwh, pwl, qwh, qwl, nhn, cn2d,
                     counts, lossAcc, ctr);
  hipLaunchKernelGGL(k_preconv, dim3(1024), dim3(256), 0, stream, x, pwh, pwl, preb, zf);
  hipLaunchKernelGGL(k_dist, dim3(512), dim3(256), 0, stream, zf, ch, nhn, q, list, ctr, lossAcc);
  hipLaunchKernelGGL(k_rescore, dim3(1024), dim3(256), 0, stream,
                     x, preW, preb, lut, cn2d, list, ctr, q);
  hipLaunchKernelGGL(k_post, dim3(1024), dim3(256), 0, stream,
                     lut, q, qwh, qwl, postb, out, counts, out_q);
  hipLaunchKernelGGL(k_fin, dim3(1), dim3(256), 0, stream, lossAcc, counts, out_loss, out_perp);
}

// Round 9
// 192.427 us; speedup vs baseline: 1.1981x; 1.1981x over previous
//
#include <hip/hip_runtime.h>
#include <cstdint>

#define NB   64
#define ND   256
#define NHW  1024
#define NTOK 65536
#define NDC  128
#define NK   1024

#define OFF_LOSS 16777216
#define OFF_Q    16777217
#define OFF_PERP 16842753

#define GAPTHR 1e-3f
#define NEGINF (-3.402823466e38f)

typedef short short8 __attribute__((ext_vector_type(8)));
typedef float f32x4 __attribute__((ext_vector_type(4)));

__device__ __forceinline__ unsigned short f2bf(float f) {
  unsigned u = __float_as_uint(f);
  u += 0x7FFFu + ((u >> 16) & 1u);
  return (unsigned short)(u >> 16);
}
__device__ __forceinline__ float bf2f(unsigned short h) {
  return __uint_as_float(((unsigned)h) << 16);
}

__device__ __forceinline__ void gll16(const void* g, void* l) {
  __builtin_amdgcn_global_load_lds(
      (const __attribute__((address_space(1))) unsigned int*)g,
      (__attribute__((address_space(3))) unsigned int*)l, 16, 0, 0);
}

// ---------- init: bf16 splits (codebook for dist, preW/postW planes), norms, zeros ----------
__global__ __launch_bounds__(256) void k_init(
    const float* __restrict__ lut, const float* __restrict__ preW,
    const float* __restrict__ postW,
    unsigned short* __restrict__ ch,
    unsigned short* __restrict__ pwh, unsigned short* __restrict__ pwl,
    unsigned short* __restrict__ qwh, unsigned short* __restrict__ qwl,
    float* __restrict__ nhn, double* __restrict__ cn2d,
    int* __restrict__ counts, double* __restrict__ lossAcc, int* __restrict__ ctr) {
  int tid = blockIdx.x * 256 + threadIdx.x;
  int stride = gridDim.x * 256;
  for (int i = tid; i < NK * NDC; i += stride) {   // lut -> split bf16 ch[code][256] (dist)
    int code = i >> 7, c = i & 127;
    float f = lut[i];
    unsigned short h1 = f2bf(f);
    float r = f - bf2f(h1);
    ch[code * 256 + c] = h1;
    ch[code * 256 + 128 + c] = f2bf(r);
  }
  for (int i = tid; i < NDC * ND; i += stride) {   // preW [DC][D] -> trunc-split planes
    float f = preW[i];
    unsigned u = __float_as_uint(f);
    float lf = f - __uint_as_float(u & 0xffff0000u);
    pwh[i] = (unsigned short)(u >> 16);
    pwl[i] = (unsigned short)(__float_as_uint(lf) >> 16);
  }
  for (int i = tid; i < ND * NDC; i += stride) {   // postW [D][DC] -> trunc-split planes
    float f = postW[i];
    unsigned u = __float_as_uint(f);
    float lf = f - __uint_as_float(u & 0xffff0000u);
    qwh[i] = (unsigned short)(u >> 16);
    qwl[i] = (unsigned short)(__float_as_uint(lf) >> 16);
  }
  if (tid < NK) {
    float s = 0.f;
    double sd = 0.0;
    for (int c = 0; c < NDC; c++) {
      float v = lut[tid * NDC + c];
      s = fmaf(v, v, s);
      sd = fma((double)v, (double)v, sd);
    }
    nhn[tid] = -0.5f * s;
    cn2d[tid] = sd;
    counts[tid] = 0;
  }
  if (tid == 0) { *lossAcc = 0.0; *ctr = 0; }
}

// ---------- pre-conv v5: 256 tokens/block, dbuf LDS chunks (1KB segments), bf16-split MFMA ----
__global__ __launch_bounds__(256, 1) void k_preconv(
    const float* __restrict__ x, const unsigned short* __restrict__ pwh,
    const unsigned short* __restrict__ pwl, const float* __restrict__ pre_b,
    float* __restrict__ zf) {
  __shared__ __align__(16) float xs[2][32 * 256];  // 2 x 32 KB [ch][tok], tok XOR-swizzled
  int bx = blockIdx.x;                  // 256 blocks: 256 tokens each
  int b = bx >> 2, p0 = (bx & 3) * 256;
  int tid = threadIdx.x;
  int lane = tid & 63, w = tid >> 6;
  int g = lane >> 4, l15 = lane & 15;
  const char* xb = (const char*)(x + (size_t)b * (ND * NHW) + p0);

  // stage chunk 0 (32 ch x 256 tok; 8 gll16/thread; 1KB contiguous per wave-inst)
  #pragma unroll
  for (int i = 0; i < 8; ++i) {
    int o = i * 4096 + tid * 16;
    int chl = o >> 10;
    int col = (o & 1023) ^ (((chl >> 3) & 3) << 5);  // pre-swizzled global source
    gll16(xb + (size_t)chl * 4096 + col, ((char*)&xs[0][0]) + o);
  }
  asm volatile("s_waitcnt vmcnt(0)" ::: "memory");
  __syncthreads();

  f32x4 acc[8][4];
  #pragma unroll
  for (int rt = 0; rt < 8; ++rt)
    #pragma unroll
    for (int ct = 0; ct < 4; ++ct) acc[rt][ct] = (f32x4){0.f, 0.f, 0.f, 0.f};

  int cur = 0;
  for (int ks = 0; ks < 8; ++ks) {
    if (ks < 7) {                       // prefetch next 32-ch chunk into other buffer
      const char* gb = xb + (size_t)(ks + 1) * 32 * 4096;
      #pragma unroll
      for (int i = 0; i < 8; ++i) {
        int o = i * 4096 + tid * 16;
        int chl = o >> 10;
        int col = (o & 1023) ^ (((chl >> 3) & 3) << 5);
        gll16(gb + (size_t)chl * 4096 + col, ((char*)&xs[cur ^ 1][0]) + o);
      }
    }
    int k0 = ks * 32;
    // B fragments: x values from LDS (swizzled read), convert to bf16-split
    short8 bh[4], bl[4];
    #pragma unroll
    for (int ct = 0; ct < 4; ++ct) {
      int tok = w * 64 + ct * 16 + l15;
      int tswz = tok ^ (g << 3);
      #pragma unroll
      for (int j = 0; j < 8; ++j) {
        float f = xs[cur][(g * 8 + j) * 256 + tswz];
        unsigned u = __float_as_uint(f);
        float lf = f - __uint_as_float(u & 0xffff0000u);
        bh[ct][j] = (short)(u >> 16);
        bl[ct][j] = (short)(__float_as_uint(lf) >> 16);
      }
    }
    #pragma unroll
    for (int rt = 0; rt < 8; ++rt) {
      short8 ah = *reinterpret_cast<const short8*>(&pwh[(rt * 16 + l15) * ND + k0 + g * 8]);
      short8 al = *reinterpret_cast<const short8*>(&pwl[(rt * 16 + l15) * ND + k0 + g * 8]);
      #pragma unroll
      for (int ct = 0; ct < 4; ++ct) {
        acc[rt][ct] = __builtin_amdgcn_mfma_f32_16x16x32_bf16(ah, bh[ct], acc[rt][ct], 0, 0, 0);
        acc[rt][ct] = __builtin_amdgcn_mfma_f32_16x16x32_bf16(ah, bl[ct], acc[rt][ct], 0, 0, 0);
        acc[rt][ct] = __builtin_amdgcn_mfma_f32_16x16x32_bf16(al, bh[ct], acc[rt][ct], 0, 0, 0);
      }
    }
    asm volatile("s_waitcnt vmcnt(0)" ::: "memory");
    __syncthreads();
    cur ^= 1;
  }

  #pragma unroll
  for (int rt = 0; rt < 8; ++rt) {
    float4 bb = *reinterpret_cast<const float4*>(&pre_b[rt * 16 + g * 4]);
    #pragma unroll
    for (int ct = 0; ct < 4; ++ct) {
      int n = bx * 256 + w * 64 + ct * 16 + l15;
      float4 v;
      v.x = acc[rt][ct][0] + bb.x;
      v.y = acc[rt][ct][1] + bb.y;
      v.z = acc[rt][ct][2] + bb.z;
      v.w = acc[rt][ct][3] + bb.w;
      *reinterpret_cast<float4*>(&zf[(size_t)n * NDC + rt * 16 + g * 4]) = v;
    }
  }
}

// ---------- distance via bf16-split MFMA + fused loss: argmax_k (z.c - 0.5|c|^2) ----------
__global__ __launch_bounds__(256, 2) void k_dist(
    const float* __restrict__ zf, const unsigned short* __restrict__ ch,
    const float* __restrict__ nhn,
    int* __restrict__ q, int* __restrict__ list, int* __restrict__ ctr,
    double* __restrict__ lossAcc) {
  __shared__ __align__(16) short chbuf[2][16384];   // 2 x 32 KB code chunk (swizzled image)
  __shared__ float HnLds[NK];                       // 4 KB (negated half-norms)
  __shared__ float zn2Lds[4][2][16];                // |z|^2 per token
  __shared__ float red[256];
  int tid = threadIdx.x;
  int lane = tid & 63, w = tid >> 6;
  int g = lane >> 4;
  int n0 = blockIdx.x * 128;

  for (int i = tid; i < NK; i += 256) HnLds[i] = nhn[i];

  // A fragments: 32 tokens per wave, bf16-split in registers (z1 in [0..3], z2 in [4..7])
  short8 az[2][8];
  {
    int arow = lane & 15;
    #pragma unroll
    for (int rt = 0; rt < 2; ++rt) {
      const float* zr = zf + (size_t)(n0 + w * 32 + rt * 16 + arow) * NDC;
      float sq = 0.f;
      #pragma unroll
      for (int f = 0; f < 4; ++f) {
        const float* p = zr + f * 32 + g * 8;
        float4 v0 = *reinterpret_cast<const float4*>(p);
        float4 v1 = *reinterpret_cast<const float4*>(p + 4);
        float vv[8] = {v0.x, v0.y, v0.z, v0.w, v1.x, v1.y, v1.z, v1.w};
        short8 hi, lo;
        #pragma unroll
        for (int j = 0; j < 8; ++j) {
          sq = fmaf(vv[j], vv[j], sq);
          unsigned short h1 = f2bf(vv[j]);
          float r = vv[j] - bf2f(h1);
          hi[j] = (short)h1;
          lo[j] = (short)f2bf(r);
        }
        az[rt][f] = hi;
        az[rt][4 + f] = lo;
      }
      sq += __shfl_xor(sq, 16, 64);
      sq += __shfl_xor(sq, 32, 64);
      if (g == 0) zn2Lds[w][rt][arow] = sq;   // full |z|^2 of token n0+w*32+rt*16+arow
    }
  }

  float best[2][4], sec[2][4];
  int bidx[2][4];
  #pragma unroll
  for (int rt = 0; rt < 2; ++rt)
    #pragma unroll
    for (int r = 0; r < 4; ++r) { best[rt][r] = NEGINF; sec[rt][r] = NEGINF; bidx[rt][r] = 0; }

  const char* chg = (const char*)ch;
  // stage chunk 0
  {
    const char* gb = chg + 0;
    #pragma unroll
    for (int rr = 0; rr < 8; ++rr) {
      int o = rr * 4096 + tid * 16;
      int so = o ^ (((o >> 9) & 7) << 4);
      gll16(gb + so, ((char*)&chbuf[0][0]) + o);
    }
  }
  asm volatile("s_waitcnt vmcnt(0)" ::: "memory");
  __syncthreads();

  int cur = 0;
  for (int chunk = 0; chunk < 16; ++chunk) {
    if (chunk < 15) {                         // prefetch next chunk into other buffer
      const char* gb = chg + (chunk + 1) * 32768;
      #pragma unroll
      for (int rr = 0; rr < 8; ++rr) {
        int o = rr * 4096 + tid * 16;
        int so = o ^ (((o >> 9) & 7) << 4);
        gll16(gb + so, ((char*)&chbuf[cur ^ 1][0]) + o);
      }
    }
    const char* cb = (const char*)&chbuf[cur][0];
    for (int ct = 0; ct < 4; ++ct) {
      int codeg = chunk * 64 + ct * 16 + (lane & 15);
      float nh = HnLds[codeg];
      short8 bc[8];
      #pragma unroll
      for (int f = 0; f < 8; ++f) {
        int byte = ((lane & 15) + ct * 16) * 512 + f * 64 + g * 16;
        byte ^= ((lane & 7) << 4);
        bc[f] = *reinterpret_cast<const short8*>(cb + byte);
      }
      f32x4 acc0 = {nh, nh, nh, nh};
      f32x4 acc1 = {nh, nh, nh, nh};
      #pragma unroll
      for (int j = 0; j < 4; ++j) {
        acc0 = __builtin_amdgcn_mfma_f32_16x16x32_bf16(az[0][j], bc[j], acc0, 0, 0, 0);
        acc1 = __builtin_amdgcn_mfma_f32_16x16x32_bf16(az[1][j], bc[j], acc1, 0, 0, 0);
        acc0 = __builtin_amdgcn_mfma_f32_16x16x32_bf16(az[0][j], bc[4 + j], acc0, 0, 0, 0);
        acc1 = __builtin_amdgcn_mfma_f32_16x16x32_bf16(az[1][j], bc[4 + j], acc1, 0, 0, 0);
        acc0 = __builtin_amdgcn_mfma_f32_16x16x32_bf16(az[0][4 + j], bc[j], acc0, 0, 0, 0);
        acc1 = __builtin_amdgcn_mfma_f32_16x16x32_bf16(az[1][4 + j], bc[j], acc1, 0, 0, 0);
      }
      #pragma unroll
      for (int r = 0; r < 4; ++r) {
        float s0 = acc0[r];
        bool t0 = s0 > best[0][r];
        bidx[0][r] = t0 ? codeg : bidx[0][r];
        sec[0][r] = fmaxf(sec[0][r], fminf(s0, best[0][r]));
        best[0][r] = fmaxf(s0, best[0][r]);
        float s1 = acc1[r];
        bool t1 = s1 > best[1][r];
        bidx[1][r] = t1 ? codeg : bidx[1][r];
        sec[1][r] = fmaxf(sec[1][r], fminf(s1, best[1][r]));
        best[1][r] = fmaxf(s1, best[1][r]);
      }
    }
    asm volatile("s_waitcnt vmcnt(0)" ::: "memory");
    __syncthreads();
    cur ^= 1;
  }

  // cross-lane merge over the 16 code-columns (lanes sharing g), write q/list, loss partials
  float lsum = 0.f;
  #pragma unroll
  for (int rt = 0; rt < 2; ++rt) {
    #pragma unroll
    for (int r = 0; r < 4; ++r) {
      float b = best[rt][r];
      float s2 = sec[rt][r];
      int bi_ = bidx[rt][r];
      #pragma unroll
      for (int m = 1; m < 16; m <<= 1) {
        float ob = __shfl_xor(b, m, 64);
        float os = __shfl_xor(s2, m, 64);
        int oi = __shfl_xor(bi_, m, 64);
        float ns = fmaxf(fmaxf(s2, os), fminf(b, ob));
        bool take = (ob > b) || (ob == b && oi < bi_);
        b = take ? ob : b;
        bi_ = take ? oi : bi_;
        s2 = ns;
      }
      if ((lane & 15) == 0) {
        int token = n0 + w * 32 + rt * 16 + g * 4 + r;
        q[token] = bi_;
        if (b - s2 < GAPTHR) {
          int pos = atomicAdd(ctr, 1);
          list[pos] = token;
        }
        lsum += zn2Lds[w][rt][g * 4 + r] - 2.0f * b;  // |z - c|^2 = |z|^2 - 2 s*
      }
    }
  }
  red[tid] = lsum;
  __syncthreads();
  for (int s = 128; s > 0; s >>= 1) {
    if (tid < s) red[tid] += red[tid + s];
    __syncthreads();
  }
  if (tid == 0) atomicAdd(lossAcc, (double)red[0]);
}

// ---------- rescore v3: 4 tokens/block-iter, fully thread-parallel f64 ----------
__global__ __launch_bounds__(256) void k_rescore(
    const float* __restrict__ x, const float* __restrict__ preW,
    const float* __restrict__ pre_b, const float* __restrict__ lut,
    const double* __restrict__ cn2d,
    const int* __restrict__ list, const int* __restrict__ ctr, int* __restrict__ q) {
  __shared__ float xs[4][256];
  __shared__ double zs[4][128];
  __shared__ double rd[4][256];
  __shared__ int    rc[4][256];
  int nf = *ctr;
  int tid = threadIdx.x;
  int w = tid >> 6, lane = tid & 63;
  for (int g0 = blockIdx.x * 4; g0 < nf; g0 += gridDim.x * 4) {
    int nt = nf - g0; if (nt > 4) nt = 4;
    // phase 0: stage the 4 x-columns (d = tid)
    #pragma unroll
    for (int t = 0; t < 4; ++t) {
      int token = list[g0 + (t < nt ? t : 0)];
      int b = token >> 10, p = token & 1023;
      xs[t][tid] = x[(size_t)(b * ND + tid) * NHW + p];
    }
    __syncthreads();
    // phase 1: z in f64 — 512 (token,dc) tasks over 256 threads x 2 reps
    #pragma unroll
    for (int rep = 0; rep < 2; ++rep) {
      int idx = rep * 256 + tid;
      int t = idx >> 7, dc = idx & 127;
      double acc = (double)pre_b[dc];
      const float* wr = preW + (size_t)dc * ND;
      #pragma unroll 4
      for (int d = 0; d < ND; d += 4) {
        float4 wv = *reinterpret_cast<const float4*>(wr + d);
        acc = fma((double)wv.x, (double)xs[t][d + 0], acc);
        acc = fma((double)wv.y, (double)xs[t][d + 1], acc);
        acc = fma((double)wv.z, (double)xs[t][d + 2], acc);
        acc = fma((double)wv.w, (double)xs[t][d + 3], acc);
      }
      zs[t][dc] = acc;
    }
    __syncthreads();
    // phase 2: each thread scans 4 codes (ascending) for all 4 tokens
    double bd[4]; int bc_[4];
    #pragma unroll
    for (int t = 0; t < 4; ++t) { bd[t] = 1e300; bc_[t] = 0x7fffffff; }
    for (int cc = 0; cc < 4; ++cc) {
      int c = cc * 256 + tid;
      const float* cr = lut + (size_t)c * NDC;
      double a0 = 0.0, a1 = 0.0, a2 = 0.0, a3 = 0.0;
      #pragma unroll 4
      for (int k = 0; k < NDC; ++k) {
        double lc = (double)cr[k];
        a0 = fma(zs[0][k], lc, a0);
        a1 = fma(zs[1][k], lc, a1);
        a2 = fma(zs[2][k], lc, a2);
        a3 = fma(zs[3][k], lc, a3);
      }
      double cn = cn2d[c];
      double d0 = cn - 2.0 * a0; if (d0 < bd[0]) { bd[0] = d0; bc_[0] = c; }
      double d1 = cn - 2.0 * a1; if (d1 < bd[1]) { bd[1] = d1; bc_[1] = c; }
      double d2 = cn - 2.0 * a2; if (d2 < bd[2]) { bd[2] = d2; bc_[2] = c; }
      double d3 = cn - 2.0 * a3; if (d3 < bd[3]) { bd[3] = d3; bc_[3] = c; }
    }
    #pragma unroll
    for (int t = 0; t < 4; ++t) { rd[t][tid] = bd[t]; rc[t][tid] = bc_[t]; }
    __syncthreads();
    // phase 3: wave w reduces token w (tree, lowest-index tie-break)
    {
      double b_ = rd[w][lane]; int c_ = rc[w][lane];
      #pragma unroll
      for (int s = 64; s < 256; s += 64) {
        double ob = rd[w][lane + s]; int oc = rc[w][lane + s];
        if (ob < b_ || (ob == b_ && oc < c_)) { b_ = ob; c_ = oc; }
      }
      #pragma unroll
      for (int m = 1; m < 64; m <<= 1) {
        double ob = __shfl_xor(b_, m, 64);
        int oc = __shfl_xor(c_, m, 64);
        if (ob < b_ || (ob == b_ && oc < c_)) { b_ = ob; c_ = oc; }
      }
      if (lane == 0 && w < nt) q[list[g0 + w]] = c_;
    }
    __syncthreads();
  }
}

// ---------- post-conv via bf16-split MFMA: lut gathers hoisted, float4 stores ----------
__global__ __launch_bounds__(256, 3) void k_post(
    const float* __restrict__ lut,
    const int* __restrict__ q, const unsigned short* __restrict__ qwh,
    const unsigned short* __restrict__ qwl, const float* __restrict__ post_b,
    float* __restrict__ out,
    int* __restrict__ counts, float* __restrict__ outq) {
  int bx = blockIdx.x;                       // 1024 blocks: (512 token sets) x (2 o-halves)
  int n0 = (bx >> 1) * 128;
  int oh = (bx & 1) * 128;
  int b = n0 >> 10, p0 = n0 & 1023;
  int tid = threadIdx.x;
  int lane = tid & 63, w = tid >> 6;
  int g = lane >> 4, l15 = lane & 15;

  int qv[2];
  #pragma unroll
  for (int ct = 0; ct < 2; ++ct) qv[ct] = q[n0 + w * 32 + ct * 16 + l15];

  // hoist ALL lut gathers (the long dependent chain) before any compute
  float4 ga[2][4][2];
  #pragma unroll
  for (int ct = 0; ct < 2; ++ct) {
    const float* xr0 = lut + (size_t)qv[ct] * NDC + g * 8;
    #pragma unroll
    for (int ks = 0; ks < 4; ++ks) {
      ga[ct][ks][0] = *reinterpret_cast<const float4*>(xr0 + ks * 32);
      ga[ct][ks][1] = *reinterpret_cast<const float4*>(xr0 + ks * 32 + 4);
    }
  }

  // histogram + q_map: each block handles its own 64-token half
  if (tid < 64) {
    int n = n0 + ((bx & 1) << 6) + tid;
    int c = q[n];
    atomicAdd(&counts[c], 1);
    outq[n] = (float)c;
  }

  // convert all gathers to bf16-split A fragments
  short8 ah[2][4], al[2][4];
  #pragma unroll
  for (int ct = 0; ct < 2; ++ct)
    #pragma unroll
    for (int ks = 0; ks < 4; ++ks) {
      float vv[8] = {ga[ct][ks][0].x, ga[ct][ks][0].y, ga[ct][ks][0].z, ga[ct][ks][0].w,
                     ga[ct][ks][1].x, ga[ct][ks][1].y, ga[ct][ks][1].z, ga[ct][ks][1].w};
      #pragma unroll
      for (int j = 0; j < 8; ++j) {
        unsigned u = __float_as_uint(vv[j]);
        float lf = vv[j] - __uint_as_float(u & 0xffff0000u);
        ah[ct][ks][j] = (short)(u >> 16);
        al[ct][ks][j] = (short)(__float_as_uint(lf) >> 16);
      }
    }

  f32x4 acc[8][2];
  #pragma unroll
  for (int nt = 0; nt < 8; ++nt)
    #pragma unroll
    for (int ct = 0; ct < 2; ++ct) acc[nt][ct] = (f32x4){0.f, 0.f, 0.f, 0.f};

  #pragma unroll
  for (int ks = 0; ks < 4; ++ks) {
    int k0 = ks * 32;
    #pragma unroll
    for (int nt = 0; nt < 8; ++nt) {
      short8 bh = *reinterpret_cast<const short8*>(&qwh[(size_t)(oh + nt * 16 + l15) * NDC + k0 + g * 8]);
      short8 bl = *reinterpret_cast<const short8*>(&qwl[(size_t)(oh + nt * 16 + l15) * NDC + k0 + g * 8]);
      #pragma unroll
      for (int ct = 0; ct < 2; ++ct) {
        acc[nt][ct] = __builtin_amdgcn_mfma_f32_16x16x32_bf16(ah[ct][ks], bh, acc[nt][ct], 0, 0, 0);
        acc[nt][ct] = __builtin_amdgcn_mfma_f32_16x16x32_bf16(al[ct][ks], bh, acc[nt][ct], 0, 0, 0);
        acc[nt][ct] = __builtin_amdgcn_mfma_f32_16x16x32_bf16(ah[ct][ks], bl, acc[nt][ct], 0, 0, 0);
      }
    }
  }
  // store: acc[nt][ct] holds 4 consecutive tokens (p) at fixed o -> float4 stores
  #pragma unroll
  for (int nt = 0; nt < 8; ++nt) {
    int o = oh + nt * 16 + l15;
    float bias = post_b[o];
    float* orow = out + (size_t)(b * ND + o) * NHW;
    #pragma unroll
    for (int ct = 0; ct < 2; ++ct) {
      int p = p0 + w * 32 + ct * 16 + g * 4;
      float4 v;
      v.x = acc[nt][ct][0] + bias;
      v.y = acc[nt][ct][1] + bias;
      v.z = acc[nt][ct][2] + bias;
      v.w = acc[nt][ct][3] + bias;
      *reinterpret_cast<float4*>(orow + p) = v;
    }
  }
}

// ---------- finalize ----------
__global__ __launch_bounds__(256) void k_fin(
    const double* __restrict__ lossAcc, const int* __restrict__ counts,
    float* __restrict__ out_loss, float* __restrict__ out_perp) {
  __shared__ float red[256];
  int tid = threadIdx.x;
  float h = 0.f;
  for (int i = tid; i < NK; i += 256) {
    float e = (float)counts[i] * (1.0f / (float)NTOK);
    h += e * logf(e + 1e-10f);
  }
  red[tid] = h;
  __syncthreads();
  for (int s = 128; s > 0; s >>= 1) {
    if (tid < s) red[tid] += red[tid + s];
    __syncthreads();
  }
  if (tid == 0) {
    *out_perp = expf(-red[0]);
    *out_loss = (float)(*lossAcc / ((double)NTOK * (double)NDC));
  }
}

extern "C" void kernel_launch(void* const* d_in, const int* in_sizes, int n_in,
                              void* d_out, int out_size, void* d_ws, size_t ws_size,
                              hipStream_t stream) {
  const float* x     = (const float*)d_in[0];
  const float* preW  = (const float*)d_in[1];
  const float* preb  = (const float*)d_in[2];
  const float* postW = (const float*)d_in[3];
  const float* postb = (const float*)d_in[4];
  const float* lut   = (const float*)d_in[5];
  float* out = (float*)d_out;

  char* ws = (char*)d_ws;
  float*          zf      = (float*)(ws);                      // 33,554,432 B
  unsigned short* ch      = (unsigned short*)(ws + 33554432);  //   524,288 B
  unsigned short* pwh     = (unsigned short*)(ws + 34078720);  //    65,536 B
  unsigned short* pwl     = (unsigned short*)(ws + 34144256);  //    65,536 B
  unsigned short* qwh     = (unsigned short*)(ws + 34209792);  //    65,536 B
  unsigned short* qwl     = (unsigned short*)(ws + 34275328);  //    65,536 B
  float*          nhn     = (float*)(ws + 34340864);           //     4,096 B
  int*            q       = (int*)  (ws + 34344960);           //   262,144 B
  int*            list    = (int*)  (ws + 34607104);           //   262,144 B
  int*            counts  = (int*)  (ws + 34869248);           //     4,096 B
  double*         lossAcc = (double*)(ws + 34873344);          //         8 B
  int*            ctr     = (int*)  (ws + 34873352);           //         4 B
  double*         cn2d    = (double*)(ws + 34873360);          //     8,192 B

  float* out_loss = out + OFF_LOSS;
  float* out_q    = out + OFF_Q;
  float* out_perp = out + OFF_PERP;

  hipLaunchKernelGGL(k_init, dim3(512), dim3(256), 0, stream,
                     lut, preW, postW, ch, pwh, pwl, qwh, qwl, nhn, cn2d,
                     counts, lossAcc, ctr);
  hipLaunchKernelGGL(k_preconv, dim3(256), dim3(256), 0, stream, x, pwh, pwl, preb, zf);
  hipLaunchKernelGGL(k_dist, dim3(512), dim3(256), 0, stream, zf, ch, nhn, q, list, ctr, lossAcc);
  hipLaunchKernelGGL(k_rescore, dim3(1024), dim3(256), 0, stream,
                     x, preW, preb, lut, cn2d, list, ctr, q);
  hipLaunchKernelGGL(k_post, dim3(1024), dim3(256), 0, stream,
                     lut, q, qwh, qwl, postb, out, counts, out_q);
  hipLaunchKernelGGL(k_fin, dim3(1), dim3(256), 0, stream, lossAcc, counts, out_loss, out_perp);
}